// Round 14
// baseline (370.166 us; speedup 1.0000x reference)
//
#include <hip/hip_runtime.h>

#define NN 512
#define CCH 128
#define MM (NN*NN)   // 262144

using f32x4  = __attribute__((ext_vector_type(4))) float;
using f32x2  = __attribute__((ext_vector_type(2))) float;
using bf16x8 = __attribute__((ext_vector_type(8))) short;
using u16x4  = __attribute__((ext_vector_type(4))) unsigned short;
using u32x2  = __attribute__((ext_vector_type(2))) unsigned int;
using u32x4  = __attribute__((ext_vector_type(4))) unsigned int;
typedef unsigned short u16;

__device__ __forceinline__ u16 f2bf(float f) {
    unsigned u = __builtin_bit_cast(unsigned, f);
    u += 0x7FFF + ((u >> 16) & 1);
    return (u16)(u >> 16);
}
__device__ __forceinline__ float bf2f(u16 h) {
    unsigned u = ((unsigned)h) << 16;
    return __builtin_bit_cast(float, u);
}
__device__ __forceinline__ unsigned pack2(float lo, float hi) {
    return (unsigned)f2bf(lo) | ((unsigned)f2bf(hi) << 16);
}
__device__ __forceinline__ float sigm(float x) { return 1.0f / (1.0f + __expf(-x)); }

__device__ __forceinline__ void gl_lds16(const void* g, void* l) {
    __builtin_amdgcn_global_load_lds(
        (const __attribute__((address_space(1))) void*)g,
        (__attribute__((address_space(3))) void*)l, 16, 0, 0);
}

// ---------------- k_prep: fold LN gamma/beta into bf16 weights + biases ----
__global__ __launch_bounds__(256) void k_prep(
    const float* __restrict__ w0, const float* __restrict__ w1,
    const float* __restrict__ w2, const float* __restrict__ w3,
    const float* __restrict__ w4, const float* __restrict__ w5,
    const float* __restrict__ b0, const float* __restrict__ b1,
    const float* __restrict__ b2, const float* __restrict__ b3,
    const float* __restrict__ b4, const float* __restrict__ b5,
    const float* __restrict__ gin, const float* __restrict__ bin,
    const float* __restrict__ gout, const float* __restrict__ bout,
    u16* __restrict__ wbf, float* __restrict__ bias2) {
    int mat = blockIdx.x;
    const float* W = mat==0?w0:mat==1?w1:mat==2?w2:mat==3?w3:mat==4?w4:w5;
    const float* B = mat==0?b0:mat==1?b1:mat==2?b2:mat==3?b3:mat==4?b4:b5;
    const float* G = (mat==5)? gout : gin;
    const float* Bt= (mat==5)? bout : bin;
    __shared__ float gs[CCH], bs[CCH];
    int tid = threadIdx.x;
    if (tid < CCH) { gs[tid] = G[tid]; bs[tid] = Bt[tid]; }
    __syncthreads();
    int o = tid >> 1, c0 = (tid & 1) * 64;
    const float* src = W + o * CCH + c0;
    char* dstrow = (char*)(wbf + mat * 16384) + o * 256;
    int key = o & 7;
    float dot = 0.f;
    #pragma unroll
    for (int q = 0; q < 16; ++q) {
        f32x4 v = *(const f32x4*)(src + q * 4);
        int c = c0 + q * 4;
        dot += bs[c]*v.x + bs[c+1]*v.y + bs[c+2]*v.z + bs[c+3]*v.w;
        u16x4 p;
        p.x = f2bf(v.x * gs[c]);     p.y = f2bf(v.y * gs[c+1]);
        p.z = f2bf(v.z * gs[c+2]);   p.w = f2bf(v.w * gs[c+3]);
        int chunk = (c0 >> 3) + (q >> 1);
        *(u16x4*)(dstrow + (((chunk ^ key)) << 4) + ((q & 1) << 3)) = p;
    }
    dot += __shfl_xor(dot, 1);
    if ((tid & 1) == 0) bias2[mat * CCH + o] = B[o] + dot;
}

// ---------------- k_fused: LN + 5 projections, 256 rows/block, 2 tiles/wave
// Each B-fragment LDS read feeds 2 m-tiles (halves LDS traffic).
// nt-half split keeps acc at 64 VGPRs -> 4 waves/SIMD preserved.
__global__ __launch_bounds__(512, 4) void k_fused(
    const float* __restrict__ z, const float* __restrict__ mask,
    const u16* __restrict__ wbf, const float* __restrict__ bias2,
    u16* __restrict__ aT, u16* __restrict__ bT, u16* gateB) {
    __shared__ __align__(16) u16 wls[32768];   // 64KB: two 32KB weight matrices
    int tid = threadIdx.x, w = tid >> 6, lane = tid & 63;
    int r = lane & 15, kq = lane >> 4;
    long m0 = (long)blockIdx.x * 256;

    // stage pair-A weights (mats 0,1 contiguous 64KB) — hides under LN
    {
        const char* Wg = (const char*)wbf;
        #pragma unroll
        for (int it = 0; it < 8; ++it)
            gl_lds16(Wg + (long)it * 8192 + tid * 16, (char*)wls + it * 8192 + w * 1024);
    }

    // LN in registers for both tiles
    bf16x8 av[2][4];
    #pragma unroll
    for (int t = 0; t < 2; ++t) {
        const float* zr = z + (m0 + t * 128 + w * 16 + r) * CCH;
        f32x4 zv[4][2];
        float s = 0.f, s2 = 0.f;
        #pragma unroll
        for (int kb = 0; kb < 4; ++kb) {
            zv[kb][0] = *(const f32x4*)(zr + kb * 32 + kq * 8);
            zv[kb][1] = *(const f32x4*)(zr + kb * 32 + kq * 8 + 4);
            #pragma unroll
            for (int h = 0; h < 2; ++h) {
                f32x4 v = zv[kb][h];
                s += v.x + v.y + v.z + v.w;
                s2 = fmaf(v.x, v.x, fmaf(v.y, v.y, fmaf(v.z, v.z, fmaf(v.w, v.w, s2))));
            }
        }
        s  += __shfl_xor(s, 16);  s  += __shfl_xor(s, 32);
        s2 += __shfl_xor(s2, 16); s2 += __shfl_xor(s2, 32);
        float mu = s * (1.0f / CCH);
        float var = fmaxf(s2 * (1.0f / CCH) - mu * mu, 0.f);
        float rs = rsqrtf(var + 1e-5f);
        #pragma unroll
        for (int kb = 0; kb < 4; ++kb) {
            f32x4 a0 = zv[kb][0], a1 = zv[kb][1];
            u32x4 o;
            o[0] = pack2((a0.x - mu) * rs, (a0.y - mu) * rs);
            o[1] = pack2((a0.z - mu) * rs, (a0.w - mu) * rs);
            o[2] = pack2((a1.x - mu) * rs, (a1.y - mu) * rs);
            o[3] = pack2((a1.z - mu) * rs, (a1.w - mu) * rs);
            av[t][kb] = __builtin_bit_cast(bf16x8, o);
        }
    }
    f32x4 mkv[2];
    mkv[0] = *(const f32x4*)(mask + m0 + w * 16 + kq * 4);
    mkv[1] = *(const f32x4*)(mask + m0 + 128 + w * 16 + kq * 4);

    int i7 = (int)((blockIdx.x >> 1) & 7);
    int q = w * 2 + (kq >> 1);
    long bo_base = ((long)(q >> 3) << 7) + ((long)((q & 7) ^ i7) << 4) + ((kq & 1) << 3);
    long boff0 = m0 * 2 + bo_base;
    long boff1 = (m0 + 128) * 2 + bo_base;

    f32x4 acc1[2][4], acc2[2][4];

    // pair MFMA half: nt in [nb, nb+4), both matrices, both tiles
    auto mfma_half = [&](int nb) {
        #pragma unroll
        for (int tt = 0; tt < 2; ++tt)
            #pragma unroll
            for (int nt = 0; nt < 4; ++nt) { acc1[tt][nt] = {0,0,0,0}; acc2[tt][nt] = {0,0,0,0}; }
        #pragma unroll
        for (int nt = 0; nt < 4; ++nt) {
            int ol = (nb + nt) * 16 + r;
            int key = ol & 7;
            const char* row1 = (const char*)wls + ol * 256;
            const char* row2 = row1 + 32768;
            #pragma unroll
            for (int kb = 0; kb < 4; ++kb) {
                int ph16 = ((kb * 4 + kq) ^ key) << 4;
                bf16x8 b1 = *(const bf16x8*)(row1 + ph16);
                bf16x8 b2 = *(const bf16x8*)(row2 + ph16);
                acc1[0][nt] = __builtin_amdgcn_mfma_f32_16x16x32_bf16(av[0][kb], b1, acc1[0][nt], 0, 0, 0);
                acc1[1][nt] = __builtin_amdgcn_mfma_f32_16x16x32_bf16(av[1][kb], b1, acc1[1][nt], 0, 0, 0);
                acc2[0][nt] = __builtin_amdgcn_mfma_f32_16x16x32_bf16(av[0][kb], b2, acc2[0][nt], 0, 0, 0);
                acc2[1][nt] = __builtin_amdgcn_mfma_f32_16x16x32_bf16(av[1][kb], b2, acc2[1][nt], 0, 0, 0);
            }
        }
    };
    // pair epilogue half -> dst
    auto epi_half = [&](u16* dst, int nb, int mat1) {
        #pragma unroll
        for (int nt = 0; nt < 4; ++nt) {
            int cc = (nb + nt) * 16 + r;
            float bb1 = bias2[mat1 * CCH + cc];
            float bb2 = bias2[(mat1 + 1) * CCH + cc];
            long plane = (long)cc << 19;
            #pragma unroll
            for (int t = 0; t < 2; ++t) {
                f32x4 a1 = acc1[t][nt], a2 = acc2[t][nt];
                float v0 = mkv[t][0] * sigm(a1[0] + bb1) * (a2[0] + bb2);
                float v1 = mkv[t][1] * sigm(a1[1] + bb1) * (a2[1] + bb2);
                float v2 = mkv[t][2] * sigm(a1[2] + bb1) * (a2[2] + bb2);
                float v3 = mkv[t][3] * sigm(a1[3] + bb1) * (a2[3] + bb2);
                u32x2 pv; pv.x = pack2(v0, v1); pv.y = pack2(v2, v3);
                *(u32x2*)((char*)dst + plane + (t ? boff1 : boff0)) = pv;
            }
        }
    };

    __syncthreads();   // pair-A staging drained

    // ===== pair A -> aT =====
    mfma_half(0);
    epi_half(aT, 0, 0);
    mfma_half(4);
    __syncthreads();   // all pair-A wls reads done
    {   // issue pair-B staging (mats 2,3) — hides under deferred epilogue
        const char* Wg = (const char*)wbf + 65536;
        #pragma unroll
        for (int it = 0; it < 8; ++it)
            gl_lds16(Wg + (long)it * 8192 + tid * 16, (char*)wls + it * 8192 + w * 1024);
    }
    epi_half(aT, 4, 0);
    __syncthreads();   // pair-B staged & visible

    // ===== pair B -> bT =====
    mfma_half(0);
    epi_half(bT, 0, 2);
    mfma_half(4);
    __syncthreads();   // all pair-B wls reads done
    {   // issue gate staging (mat 4, 32KB)
        const char* Wg = (const char*)wbf + 131072;
        #pragma unroll
        for (int it = 0; it < 4; ++it)
            gl_lds16(Wg + (long)it * 8192 + tid * 16, (char*)wls + it * 8192 + w * 1024);
    }
    epi_half(bT, 4, 2);
    __syncthreads();   // gate staged & visible

    // ===== gate: mfma(W, zn) swapped; j-regs = 4 consecutive c =====
    #pragma unroll
    for (int nb = 0; nb < 8; nb += 4) {
        f32x4 ga[2][4];
        #pragma unroll
        for (int tt = 0; tt < 2; ++tt)
            #pragma unroll
            for (int nt = 0; nt < 4; ++nt) ga[tt][nt] = {0,0,0,0};
        #pragma unroll
        for (int nt = 0; nt < 4; ++nt) {
            int ol = (nb + nt) * 16 + r;
            int key = ol & 7;
            const char* row1 = (const char*)wls + ol * 256;
            #pragma unroll
            for (int kb = 0; kb < 4; ++kb) {
                bf16x8 b1 = *(const bf16x8*)(row1 + (((kb * 4 + kq) ^ key) << 4));
                ga[0][nt] = __builtin_amdgcn_mfma_f32_16x16x32_bf16(b1, av[0][kb], ga[0][nt], 0, 0, 0);
                ga[1][nt] = __builtin_amdgcn_mfma_f32_16x16x32_bf16(b1, av[1][kb], ga[1][nt], 0, 0, 0);
            }
        }
        #pragma unroll
        for (int nt = 0; nt < 4; ++nt) {
            int c0 = (nb + nt) * 16 + kq * 4;
            f32x4 bg = *(const f32x4*)(bias2 + 4 * CCH + c0);
            #pragma unroll
            for (int t = 0; t < 2; ++t) {
                long m = m0 + t * 128 + w * 16 + r;
                u32x2 pv;
                pv.x = pack2(sigm(ga[t][nt][0] + bg[0]), sigm(ga[t][nt][1] + bg[1]));
                pv.y = pack2(sigm(ga[t][nt][2] + bg[2]), sigm(ga[t][nt][3] + bg[3]));
                *(u32x2*)(gateB + m * 256 + c0) = pv;
            }
        }
    }
}

// ---------------- k_tri: per-channel triangle GEMM, BK=64 ------------------
__global__ __launch_bounds__(256, 4) void k_tri(const u16* __restrict__ aT,
                                                const u16* __restrict__ bT,
                                                u16* __restrict__ xT) {
    __shared__ __align__(16) char shm[34816];
    u16* At = (u16*)shm;
    u16* Bt = (u16*)(shm + 16384);
    int tid = threadIdx.x;
    int w = tid >> 6, lane = tid & 63;
    int r = lane & 15, kq = lane >> 4;

    int L = blockIdx.x;
    int xcd = L & 7, idx = L >> 3;
    int c    = xcd + 8 * (idx >> 4);
    int tile = idx & 15;
    int ti = tile >> 2, tj = tile & 3;

    const char* abase = (const char*)(aT + (long)c * MM) + (long)(ti * 128) * 1024;
    const char* bbase = (const char*)(bT + (long)c * MM) + (long)(tj * 128) * 1024;
    int wm = w >> 1, wn = w & 1;

    f32x4 acc[4][4];
    #pragma unroll
    for (int a = 0; a < 4; ++a)
        #pragma unroll
        for (int bq = 0; bq < 4; ++bq) acc[a][bq] = {0.f,0.f,0.f,0.f};

    for (int ks = 0; ks < 8; ++ks) {
        const char* asrc = abase + ks * 128;
        const char* bsrc = bbase + ks * 128;
        #pragma unroll
        for (int it = 0; it < 4; ++it) {
            int u = it * 256 + tid;
            long goff = (long)(u >> 3) * 1024 + (u & 7) * 16;
            gl_lds16(asrc + goff, (char*)At + it * 4096 + w * 1024);
            gl_lds16(bsrc + goff, (char*)Bt + it * 4096 + w * 1024);
        }
        __syncthreads();

        #pragma unroll
        for (int kh = 0; kh < 2; ++kh) {
            bf16x8 af[4];
            #pragma unroll
            for (int mt = 0; mt < 4; ++mt) {
                int rowa = wm * 64 + mt * 16 + r;
                af[mt] = *(const bf16x8*)((const char*)At + rowa * 128 +
                                          (((kh * 4 + kq) ^ (r & 7)) << 4));
            }
            #pragma unroll
            for (int nt = 0; nt < 4; ++nt) {
                int rowb = wn * 64 + nt * 16 + r;
                bf16x8 bf = *(const bf16x8*)((const char*)Bt + rowb * 128 +
                                             (((kh * 4 + kq) ^ (r & 7)) << 4));
                #pragma unroll
                for (int mt = 0; mt < 4; ++mt)
                    acc[mt][nt] = __builtin_amdgcn_mfma_f32_16x16x32_bf16(bf, af[mt], acc[mt][nt], 0, 0, 0);
            }
        }
        __syncthreads();
    }

    char* tb = shm;
    #pragma unroll
    for (int mt = 0; mt < 4; ++mt) {
        int il = wm * 64 + mt * 16 + r;
        #pragma unroll
        for (int nt = 0; nt < 4; ++nt) {
            int jl = wn * 64 + nt * 16 + kq * 4;
            u32x2 pv;
            pv.x = pack2(acc[mt][nt][0], acc[mt][nt][1]);
            pv.y = pack2(acc[mt][nt][2], acc[mt][nt][3]);
            *(u32x2*)(tb + il * 272 + jl * 2) = pv;
        }
    }
    __syncthreads();
    u16* xrow = xT + (long)c * MM + (long)(ti * 128) * NN + tj * 128;
    int joff = tid & 15;
    #pragma unroll
    for (int rd = 0; rd < 8; ++rd) {
        int il = rd * 16 + (tid >> 4);
        u32x4 vv = *(const u32x4*)(tb + il * 272 + joff * 16);
        *(u32x4*)(xrow + (long)il * NN + joff * 8) = vv;
    }
}

// ---------------- k_out: LN(x) @ w_z''^T + bias2_z, * gate -----------------
__global__ __launch_bounds__(256, 4) void k_out(const u16* __restrict__ xT,
                                                const u16* __restrict__ wbf,
                                                const float* __restrict__ bias2,
                                                const u16* gateB,
                                                float* __restrict__ outp) {
    __shared__ __align__(16) u16 xl[64 * 128];
    int tid = threadIdx.x, w = tid >> 6, lane = tid & 63;
    int r = lane & 15, kq = lane >> 4;
    long m0 = (long)blockIdx.x * 64;

    {
        int cg = tid & 31, ms = tid >> 5;
        int c0 = cg * 4;
        const u16* base = xT + m0 + (long)ms * 8;
        bf16x8 v0 = *(const bf16x8*)(base + (long)(c0 + 0) * MM);
        bf16x8 v1 = *(const bf16x8*)(base + (long)(c0 + 1) * MM);
        bf16x8 v2 = *(const bf16x8*)(base + (long)(c0 + 2) * MM);
        bf16x8 v3 = *(const bf16x8*)(base + (long)(c0 + 3) * MM);
        #pragma unroll
        for (int e = 0; e < 8; ++e) {
            int m = ms * 8 + e;
            u16x4 t;
            t.x = (u16)v0[e]; t.y = (u16)v1[e]; t.z = (u16)v2[e]; t.w = (u16)v3[e];
            *(u16x4*)((char*)xl + m * 256 + ((c0 * 2) ^ ((m & 15) << 4))) = t;
        }
    }
    __syncthreads();

    int mlr = w * 16 + r;
    int swm = (mlr & 15) << 4;
    u32x4 avu[4];
    float s = 0.f, s2 = 0.f;
    #pragma unroll
    for (int kb = 0; kb < 4; ++kb) {
        avu[kb] = *(const u32x4*)((const char*)xl + mlr * 256 + ((kb * 64 + kq * 16) ^ swm));
        #pragma unroll
        for (int p = 0; p < 4; ++p) {
            unsigned u = avu[kb][p];
            float flo = __builtin_bit_cast(float, u << 16);
            float fhi = __builtin_bit_cast(float, u & 0xFFFF0000u);
            s += flo + fhi;
            s2 = fmaf(flo, flo, s2);
            s2 = fmaf(fhi, fhi, s2);
        }
    }
    s  += __shfl_xor(s, 16);  s  += __shfl_xor(s, 32);
    s2 += __shfl_xor(s2, 16); s2 += __shfl_xor(s2, 32);
    float mu = s * (1.0f / CCH);
    float var = fmaxf(s2 * (1.0f / CCH) - mu * mu, 0.f);
    float rs = rsqrtf(var + 1e-5f);
    float nmu = -mu * rs;
    bf16x8 av[4];
    #pragma unroll
    for (int kb = 0; kb < 4; ++kb) {
        u32x4 o;
        #pragma unroll
        for (int p = 0; p < 4; ++p) {
            unsigned u = avu[kb][p];
            float flo = __builtin_bit_cast(float, u << 16);
            float fhi = __builtin_bit_cast(float, u & 0xFFFF0000u);
            o[p] = pack2(fmaf(flo, rs, nmu), fmaf(fhi, rs, nmu));
        }
        av[kb] = __builtin_bit_cast(bf16x8, o);
    }

    long m = m0 + w * 16 + r;
    u16x4 gvu[8];
    f32x4 bb[8];
    #pragma unroll
    for (int nt = 0; nt < 8; ++nt) {
        gvu[nt] = *(const u16x4*)(gateB + m * 256 + nt * 16 + kq * 4);
        bb[nt]  = *(const f32x4*)(bias2 + 5 * CCH + nt * 16 + kq * 4);
    }

    const char* Wz = (const char*)(wbf + 5 * 16384);
    f32x4 acc[8];
    #pragma unroll
    for (int nt = 0; nt < 8; ++nt) acc[nt] = {0,0,0,0};
    #pragma unroll
    for (int nt = 0; nt < 8; ++nt) {
        int ol = nt * 16 + r;
        int key = ol & 7;
        const char* row = Wz + ol * 256;
        #pragma unroll
        for (int kb = 0; kb < 4; ++kb) {
            bf16x8 bw = *(const bf16x8*)(row + (((kb * 4 + kq) ^ key) << 4));
            acc[nt] = __builtin_amdgcn_mfma_f32_16x16x32_bf16(bw, av[kb], acc[nt], 0, 0, 0);
        }
    }

    __syncthreads();   // ALL gate loads done before any aliasing store

    #pragma unroll
    for (int nt = 0; nt < 8; ++nt) {
        int c0 = nt * 16 + kq * 4;
        f32x4 o;
        #pragma unroll
        for (int j = 0; j < 4; ++j)
            o[j] = (acc[nt][j] + bb[nt][j]) * bf2f(gvu[nt][j]);
        *(f32x4*)(outp + m * CCH + c0) = o;
    }
}

extern "C" void kernel_launch(void* const* d_in, const int* in_sizes, int n_in,
                              void* d_out, int out_size, void* d_ws, size_t ws_size,
                              hipStream_t stream) {
    const float* z       = (const float*)d_in[0];
    const float* mask    = (const float*)d_in[1];
    const float* ln_in_g = (const float*)d_in[2];
    const float* ln_in_b = (const float*)d_in[3];
    const float* w_ag    = (const float*)d_in[4];
    const float* b_ag    = (const float*)d_in[5];
    const float* w_ap    = (const float*)d_in[6];
    const float* b_ap    = (const float*)d_in[7];
    const float* w_bg    = (const float*)d_in[8];
    const float* b_bg    = (const float*)d_in[9];
    const float* w_bp    = (const float*)d_in[10];
    const float* b_bp    = (const float*)d_in[11];
    const float* w_g     = (const float*)d_in[12];
    const float* b_g     = (const float*)d_in[13];
    const float* w_z     = (const float*)d_in[14];
    const float* b_z     = (const float*)d_in[15];
    const float* ln_o_g  = (const float*)d_in[16];
    const float* ln_o_b  = (const float*)d_in[17];
    float* out = (float*)d_out;
    u16* gateB = (u16*)d_out;   // gate bf16 in first 256B of each 512B d_out row

    char* ws = (char*)d_ws;
    const size_t SL = (size_t)MM * CCH * 2;  // 64MB per slot
    u16* xT   = (u16*)ws;
    u16* aT   = (u16*)(ws + SL);
    u16* bT   = (u16*)(ws + 2 * SL);
    u16* wbf  = (u16*)(ws + 3 * SL);                       // 192KB swizzled bf16 weights
    float* b2 = (float*)(ws + 3 * SL + 6 * 16384 * 2);     // 3KB folded biases

    k_prep<<<6, 256, 0, stream>>>(w_ag, w_ap, w_bg, w_bp, w_g, w_z,
                                  b_ag, b_ap, b_bg, b_bp, b_g, b_z,
                                  ln_in_g, ln_in_b, ln_o_g, ln_o_b, wbf, b2);
    k_fused<<<MM / 256, 512, 0, stream>>>(z, mask, wbf, b2, aT, bT, gateB);
    k_tri<<<2048, 256, 0, stream>>>(aT, bT, xT);
    k_out<<<MM / 64, 256, 0, stream>>>(xT, wbf, b2, gateB, out);
}

// Round 15
// 301.922 us; speedup vs baseline: 1.2260x; 1.2260x over previous
//
#include <hip/hip_runtime.h>

#define NN 512
#define CCH 128
#define MM (NN*NN)   // 262144

using f32x4  = __attribute__((ext_vector_type(4))) float;
using f32x2  = __attribute__((ext_vector_type(2))) float;
using bf16x8 = __attribute__((ext_vector_type(8))) short;
using u16x4  = __attribute__((ext_vector_type(4))) unsigned short;
using u32x2  = __attribute__((ext_vector_type(2))) unsigned int;
using u32x4  = __attribute__((ext_vector_type(4))) unsigned int;
typedef unsigned short u16;

__device__ __forceinline__ u16 f2bf(float f) {
    unsigned u = __builtin_bit_cast(unsigned, f);
    u += 0x7FFF + ((u >> 16) & 1);
    return (u16)(u >> 16);
}
__device__ __forceinline__ float bf2f(u16 h) {
    unsigned u = ((unsigned)h) << 16;
    return __builtin_bit_cast(float, u);
}
__device__ __forceinline__ unsigned pack2(float lo, float hi) {
    return (unsigned)f2bf(lo) | ((unsigned)f2bf(hi) << 16);
}
__device__ __forceinline__ float sigm(float x) { return 1.0f / (1.0f + __expf(-x)); }

__device__ __forceinline__ void gl_lds16(const void* g, void* l) {
    __builtin_amdgcn_global_load_lds(
        (const __attribute__((address_space(1))) void*)g,
        (__attribute__((address_space(3))) void*)l, 16, 0, 0);
}

// ---------------- k_prep: fold LN gamma/beta into bf16 weights + biases ----
__global__ __launch_bounds__(256) void k_prep(
    const float* __restrict__ w0, const float* __restrict__ w1,
    const float* __restrict__ w2, const float* __restrict__ w3,
    const float* __restrict__ w4, const float* __restrict__ w5,
    const float* __restrict__ b0, const float* __restrict__ b1,
    const float* __restrict__ b2, const float* __restrict__ b3,
    const float* __restrict__ b4, const float* __restrict__ b5,
    const float* __restrict__ gin, const float* __restrict__ bin,
    const float* __restrict__ gout, const float* __restrict__ bout,
    u16* __restrict__ wbf, float* __restrict__ bias2) {
    int mat = blockIdx.x;
    const float* W = mat==0?w0:mat==1?w1:mat==2?w2:mat==3?w3:mat==4?w4:w5;
    const float* B = mat==0?b0:mat==1?b1:mat==2?b2:mat==3?b3:mat==4?b4:b5;
    const float* G = (mat==5)? gout : gin;
    const float* Bt= (mat==5)? bout : bin;
    __shared__ float gs[CCH], bs[CCH];
    int tid = threadIdx.x;
    if (tid < CCH) { gs[tid] = G[tid]; bs[tid] = Bt[tid]; }
    __syncthreads();
    int o = tid >> 1, c0 = (tid & 1) * 64;
    const float* src = W + o * CCH + c0;
    char* dstrow = (char*)(wbf + mat * 16384) + o * 256;
    int key = o & 7;
    float dot = 0.f;
    #pragma unroll
    for (int q = 0; q < 16; ++q) {
        f32x4 v = *(const f32x4*)(src + q * 4);
        int c = c0 + q * 4;
        dot += bs[c]*v.x + bs[c+1]*v.y + bs[c+2]*v.z + bs[c+3]*v.w;
        u16x4 p;
        p.x = f2bf(v.x * gs[c]);     p.y = f2bf(v.y * gs[c+1]);
        p.z = f2bf(v.z * gs[c+2]);   p.w = f2bf(v.w * gs[c+3]);
        int chunk = (c0 >> 3) + (q >> 1);
        *(u16x4*)(dstrow + (((chunk ^ key)) << 4) + ((q & 1) << 3)) = p;
    }
    dot += __shfl_xor(dot, 1);
    if ((tid & 1) == 0) bias2[mat * CCH + o] = B[o] + dot;
}

// ---------------- k_fused: LN + 5 projections, 256 rows/block --------------
// 512 threads; each wave owns 2 m-tiles (32 rows) so every B-fragment LDS
// read feeds 4 MFMAs. Per-nt immediate epilogue keeps acc at 16 regs
// (R14's 64-reg deferred epilogue spilled); only nt=6,7 deferred to hide
// next-stage latency.
__global__ __launch_bounds__(512, 4) void k_fused(
    const float* __restrict__ z, const float* __restrict__ mask,
    const u16* __restrict__ wbf, const float* __restrict__ bias2,
    u16* __restrict__ aT, u16* __restrict__ bT, u16* gateB) {
    __shared__ __align__(16) u16 wls[32768];   // 64KB: two 32KB weight matrices
    int tid = threadIdx.x, w = tid >> 6, lane = tid & 63;
    int r = lane & 15, kq = lane >> 4;
    long m0 = (long)blockIdx.x * 256;

    // stage pair-A weights (mats 0,1 contiguous 64KB) — hides under LN
    {
        const char* Wg = (const char*)wbf;
        #pragma unroll
        for (int it = 0; it < 8; ++it)
            gl_lds16(Wg + (long)it * 8192 + tid * 16, (char*)wls + it * 8192 + w * 1024);
    }

    // LN in registers for both tiles
    bf16x8 av[2][4];
    #pragma unroll
    for (int t = 0; t < 2; ++t) {
        const float* zr = z + (m0 + t * 128 + w * 16 + r) * CCH;
        f32x4 zv[4][2];
        float s = 0.f, s2 = 0.f;
        #pragma unroll
        for (int kb = 0; kb < 4; ++kb) {
            zv[kb][0] = *(const f32x4*)(zr + kb * 32 + kq * 8);
            zv[kb][1] = *(const f32x4*)(zr + kb * 32 + kq * 8 + 4);
            #pragma unroll
            for (int h = 0; h < 2; ++h) {
                f32x4 v = zv[kb][h];
                s += v.x + v.y + v.z + v.w;
                s2 = fmaf(v.x, v.x, fmaf(v.y, v.y, fmaf(v.z, v.z, fmaf(v.w, v.w, s2))));
            }
        }
        s  += __shfl_xor(s, 16);  s  += __shfl_xor(s, 32);
        s2 += __shfl_xor(s2, 16); s2 += __shfl_xor(s2, 32);
        float mu = s * (1.0f / CCH);
        float var = fmaxf(s2 * (1.0f / CCH) - mu * mu, 0.f);
        float rs = rsqrtf(var + 1e-5f);
        #pragma unroll
        for (int kb = 0; kb < 4; ++kb) {
            f32x4 a0 = zv[kb][0], a1 = zv[kb][1];
            u32x4 o;
            o[0] = pack2((a0.x - mu) * rs, (a0.y - mu) * rs);
            o[1] = pack2((a0.z - mu) * rs, (a0.w - mu) * rs);
            o[2] = pack2((a1.x - mu) * rs, (a1.y - mu) * rs);
            o[3] = pack2((a1.z - mu) * rs, (a1.w - mu) * rs);
            av[t][kb] = __builtin_bit_cast(bf16x8, o);
        }
    }
    f32x4 mkv[2];
    mkv[0] = *(const f32x4*)(mask + m0 + w * 16 + kq * 4);
    mkv[1] = *(const f32x4*)(mask + m0 + 128 + w * 16 + kq * 4);

    int i7 = (int)((blockIdx.x >> 1) & 7);
    int q = w * 2 + (kq >> 1);
    long bo_base = ((long)(q >> 3) << 7) + ((long)((q & 7) ^ i7) << 4) + ((kq & 1) << 3);
    long boff[2];
    boff[0] = m0 * 2 + bo_base;
    boff[1] = boff[0] + 256;

    __syncthreads();   // pair-A staging drained

    // ===== pair phases =====
    #pragma unroll 1
    for (int ph = 0; ph < 2; ++ph) {
        u16* dst = ph ? bT : aT;
        int mat1 = ph * 2;
        // nt = 0..5: MFMA + immediate epilogue (acc live = 16 regs)
        #pragma unroll
        for (int nt = 0; nt < 6; ++nt) {
            int ol = nt * 16 + r;
            int key = ol & 7;
            const char* row1 = (const char*)wls + ol * 256;
            const char* row2 = row1 + 32768;
            f32x4 a1[2] = {{0,0,0,0},{0,0,0,0}}, a2[2] = {{0,0,0,0},{0,0,0,0}};
            #pragma unroll
            for (int kb = 0; kb < 4; ++kb) {
                int ph16 = ((kb * 4 + kq) ^ key) << 4;
                bf16x8 b1 = *(const bf16x8*)(row1 + ph16);
                bf16x8 b2 = *(const bf16x8*)(row2 + ph16);
                a1[0] = __builtin_amdgcn_mfma_f32_16x16x32_bf16(av[0][kb], b1, a1[0], 0, 0, 0);
                a1[1] = __builtin_amdgcn_mfma_f32_16x16x32_bf16(av[1][kb], b1, a1[1], 0, 0, 0);
                a2[0] = __builtin_amdgcn_mfma_f32_16x16x32_bf16(av[0][kb], b2, a2[0], 0, 0, 0);
                a2[1] = __builtin_amdgcn_mfma_f32_16x16x32_bf16(av[1][kb], b2, a2[1], 0, 0, 0);
            }
            int cc = nt * 16 + r;
            float bb1 = bias2[mat1 * CCH + cc];
            float bb2 = bias2[(mat1 + 1) * CCH + cc];
            long plane = (long)cc << 19;
            #pragma unroll
            for (int t = 0; t < 2; ++t) {
                float v0 = mkv[t][0] * sigm(a1[t][0] + bb1) * (a2[t][0] + bb2);
                float v1 = mkv[t][1] * sigm(a1[t][1] + bb1) * (a2[t][1] + bb2);
                float v2 = mkv[t][2] * sigm(a1[t][2] + bb1) * (a2[t][2] + bb2);
                float v3 = mkv[t][3] * sigm(a1[t][3] + bb1) * (a2[t][3] + bb2);
                u32x2 pv; pv.x = pack2(v0, v1); pv.y = pack2(v2, v3);
                *(u32x2*)((char*)dst + plane + boff[t]) = pv;
            }
        }
        // nt = 6,7: deferred (acc live = 32 regs) to hide next-stage latency
        f32x4 d1[2][2], d2[2][2];   // [ntd][t]
        #pragma unroll
        for (int ntd = 0; ntd < 2; ++ntd) {
            int ol = (6 + ntd) * 16 + r;
            int key = ol & 7;
            const char* row1 = (const char*)wls + ol * 256;
            const char* row2 = row1 + 32768;
            d1[ntd][0] = {0,0,0,0}; d1[ntd][1] = {0,0,0,0};
            d2[ntd][0] = {0,0,0,0}; d2[ntd][1] = {0,0,0,0};
            #pragma unroll
            for (int kb = 0; kb < 4; ++kb) {
                int ph16 = ((kb * 4 + kq) ^ key) << 4;
                bf16x8 b1 = *(const bf16x8*)(row1 + ph16);
                bf16x8 b2 = *(const bf16x8*)(row2 + ph16);
                d1[ntd][0] = __builtin_amdgcn_mfma_f32_16x16x32_bf16(av[0][kb], b1, d1[ntd][0], 0, 0, 0);
                d1[ntd][1] = __builtin_amdgcn_mfma_f32_16x16x32_bf16(av[1][kb], b1, d1[ntd][1], 0, 0, 0);
                d2[ntd][0] = __builtin_amdgcn_mfma_f32_16x16x32_bf16(av[0][kb], b2, d2[ntd][0], 0, 0, 0);
                d2[ntd][1] = __builtin_amdgcn_mfma_f32_16x16x32_bf16(av[1][kb], b2, d2[ntd][1], 0, 0, 0);
            }
        }
        __syncthreads();   // all wls reads of this pair done
        // issue next staging (pair B: 64KB; gate: 32KB)
        if (ph == 0) {
            const char* Wg = (const char*)wbf + 65536;
            #pragma unroll
            for (int it = 0; it < 8; ++it)
                gl_lds16(Wg + (long)it * 8192 + tid * 16, (char*)wls + it * 8192 + w * 1024);
        } else {
            const char* Wg = (const char*)wbf + 131072;
            #pragma unroll
            for (int it = 0; it < 4; ++it)
                gl_lds16(Wg + (long)it * 8192 + tid * 16, (char*)wls + it * 8192 + w * 1024);
        }
        // deferred epilogue nt=6,7 (hides staging latency)
        #pragma unroll
        for (int ntd = 0; ntd < 2; ++ntd) {
            int cc = (6 + ntd) * 16 + r;
            float bb1 = bias2[mat1 * CCH + cc];
            float bb2 = bias2[(mat1 + 1) * CCH + cc];
            long plane = (long)cc << 19;
            #pragma unroll
            for (int t = 0; t < 2; ++t) {
                float v0 = mkv[t][0] * sigm(d1[ntd][t][0] + bb1) * (d2[ntd][t][0] + bb2);
                float v1 = mkv[t][1] * sigm(d1[ntd][t][1] + bb1) * (d2[ntd][t][1] + bb2);
                float v2 = mkv[t][2] * sigm(d1[ntd][t][2] + bb1) * (d2[ntd][t][2] + bb2);
                float v3 = mkv[t][3] * sigm(d1[ntd][t][3] + bb1) * (d2[ntd][t][3] + bb2);
                u32x2 pv; pv.x = pack2(v0, v1); pv.y = pack2(v2, v3);
                *(u32x2*)((char*)dst + plane + boff[t]) = pv;
            }
        }
        __syncthreads();   // next stage visible
    }

    // ===== gate: mfma(W, zn) swapped; j-regs = 4 consecutive c =====
    #pragma unroll
    for (int nt = 0; nt < 8; ++nt) {
        int ol = nt * 16 + r;
        int key = ol & 7;
        const char* row1 = (const char*)wls + ol * 256;
        f32x4 ga[2] = {{0,0,0,0},{0,0,0,0}};
        #pragma unroll
        for (int kb = 0; kb < 4; ++kb) {
            bf16x8 b1 = *(const bf16x8*)(row1 + (((kb * 4 + kq) ^ key) << 4));
            ga[0] = __builtin_amdgcn_mfma_f32_16x16x32_bf16(b1, av[0][kb], ga[0], 0, 0, 0);
            ga[1] = __builtin_amdgcn_mfma_f32_16x16x32_bf16(b1, av[1][kb], ga[1], 0, 0, 0);
        }
        int c0 = nt * 16 + kq * 4;
        f32x4 bg = *(const f32x4*)(bias2 + 4 * CCH + c0);
        #pragma unroll
        for (int t = 0; t < 2; ++t) {
            long m = m0 + t * 128 + w * 16 + r;
            u32x2 pv;
            pv.x = pack2(sigm(ga[t][0] + bg[0]), sigm(ga[t][1] + bg[1]));
            pv.y = pack2(sigm(ga[t][2] + bg[2]), sigm(ga[t][3] + bg[3]));
            *(u32x2*)(gateB + m * 256 + c0) = pv;
        }
    }
}

// ---------------- k_tri: per-channel triangle GEMM, BK=64 ------------------
__global__ __launch_bounds__(256, 4) void k_tri(const u16* __restrict__ aT,
                                                const u16* __restrict__ bT,
                                                u16* __restrict__ xT) {
    __shared__ __align__(16) char shm[34816];
    u16* At = (u16*)shm;
    u16* Bt = (u16*)(shm + 16384);
    int tid = threadIdx.x;
    int w = tid >> 6, lane = tid & 63;
    int r = lane & 15, kq = lane >> 4;

    int L = blockIdx.x;
    int xcd = L & 7, idx = L >> 3;
    int c    = xcd + 8 * (idx >> 4);
    int tile = idx & 15;
    int ti = tile >> 2, tj = tile & 3;

    const char* abase = (const char*)(aT + (long)c * MM) + (long)(ti * 128) * 1024;
    const char* bbase = (const char*)(bT + (long)c * MM) + (long)(tj * 128) * 1024;
    int wm = w >> 1, wn = w & 1;

    f32x4 acc[4][4];
    #pragma unroll
    for (int a = 0; a < 4; ++a)
        #pragma unroll
        for (int bq = 0; bq < 4; ++bq) acc[a][bq] = {0.f,0.f,0.f,0.f};

    for (int ks = 0; ks < 8; ++ks) {
        const char* asrc = abase + ks * 128;
        const char* bsrc = bbase + ks * 128;
        #pragma unroll
        for (int it = 0; it < 4; ++it) {
            int u = it * 256 + tid;
            long goff = (long)(u >> 3) * 1024 + (u & 7) * 16;
            gl_lds16(asrc + goff, (char*)At + it * 4096 + w * 1024);
            gl_lds16(bsrc + goff, (char*)Bt + it * 4096 + w * 1024);
        }
        __syncthreads();

        #pragma unroll
        for (int kh = 0; kh < 2; ++kh) {
            bf16x8 af[4];
            #pragma unroll
            for (int mt = 0; mt < 4; ++mt) {
                int rowa = wm * 64 + mt * 16 + r;
                af[mt] = *(const bf16x8*)((const char*)At + rowa * 128 +
                                          (((kh * 4 + kq) ^ (r & 7)) << 4));
            }
            #pragma unroll
            for (int nt = 0; nt < 4; ++nt) {
                int rowb = wn * 64 + nt * 16 + r;
                bf16x8 bf = *(const bf16x8*)((const char*)Bt + rowb * 128 +
                                             (((kh * 4 + kq) ^ (r & 7)) << 4));
                #pragma unroll
                for (int mt = 0; mt < 4; ++mt)
                    acc[mt][nt] = __builtin_amdgcn_mfma_f32_16x16x32_bf16(bf, af[mt], acc[mt][nt], 0, 0, 0);
            }
        }
        __syncthreads();
    }

    char* tb = shm;
    #pragma unroll
    for (int mt = 0; mt < 4; ++mt) {
        int il = wm * 64 + mt * 16 + r;
        #pragma unroll
        for (int nt = 0; nt < 4; ++nt) {
            int jl = wn * 64 + nt * 16 + kq * 4;
            u32x2 pv;
            pv.x = pack2(acc[mt][nt][0], acc[mt][nt][1]);
            pv.y = pack2(acc[mt][nt][2], acc[mt][nt][3]);
            *(u32x2*)(tb + il * 272 + jl * 2) = pv;
        }
    }
    __syncthreads();
    u16* xrow = xT + (long)c * MM + (long)(ti * 128) * NN + tj * 128;
    int joff = tid & 15;
    #pragma unroll
    for (int rd = 0; rd < 8; ++rd) {
        int il = rd * 16 + (tid >> 4);
        u32x4 vv = *(const u32x4*)(tb + il * 272 + joff * 16);
        *(u32x4*)(xrow + (long)il * NN + joff * 8) = vv;
    }
}

// ---------------- k_out: LN(x) @ w_z''^T + bias2_z, * gate -----------------
__global__ __launch_bounds__(256, 4) void k_out(const u16* __restrict__ xT,
                                                const u16* __restrict__ wbf,
                                                const float* __restrict__ bias2,
                                                const u16* gateB,
                                                float* __restrict__ outp) {
    __shared__ __align__(16) u16 xl[64 * 128];
    int tid = threadIdx.x, w = tid >> 6, lane = tid & 63;
    int r = lane & 15, kq = lane >> 4;
    long m0 = (long)blockIdx.x * 64;

    {
        int cg = tid & 31, ms = tid >> 5;
        int c0 = cg * 4;
        const u16* base = xT + m0 + (long)ms * 8;
        bf16x8 v0 = *(const bf16x8*)(base + (long)(c0 + 0) * MM);
        bf16x8 v1 = *(const bf16x8*)(base + (long)(c0 + 1) * MM);
        bf16x8 v2 = *(const bf16x8*)(base + (long)(c0 + 2) * MM);
        bf16x8 v3 = *(const bf16x8*)(base + (long)(c0 + 3) * MM);
        #pragma unroll
        for (int e = 0; e < 8; ++e) {
            int m = ms * 8 + e;
            u16x4 t;
            t.x = (u16)v0[e]; t.y = (u16)v1[e]; t.z = (u16)v2[e]; t.w = (u16)v3[e];
            *(u16x4*)((char*)xl + m * 256 + ((c0 * 2) ^ ((m & 15) << 4))) = t;
        }
    }
    __syncthreads();

    int mlr = w * 16 + r;
    int swm = (mlr & 15) << 4;
    u32x4 avu[4];
    float s = 0.f, s2 = 0.f;
    #pragma unroll
    for (int kb = 0; kb < 4; ++kb) {
        avu[kb] = *(const u32x4*)((const char*)xl + mlr * 256 + ((kb * 64 + kq * 16) ^ swm));
        #pragma unroll
        for (int p = 0; p < 4; ++p) {
            unsigned u = avu[kb][p];
            float flo = __builtin_bit_cast(float, u << 16);
            float fhi = __builtin_bit_cast(float, u & 0xFFFF0000u);
            s += flo + fhi;
            s2 = fmaf(flo, flo, s2);
            s2 = fmaf(fhi, fhi, s2);
        }
    }
    s  += __shfl_xor(s, 16);  s  += __shfl_xor(s, 32);
    s2 += __shfl_xor(s2, 16); s2 += __shfl_xor(s2, 32);
    float mu = s * (1.0f / CCH);
    float var = fmaxf(s2 * (1.0f / CCH) - mu * mu, 0.f);
    float rs = rsqrtf(var + 1e-5f);
    float nmu = -mu * rs;
    bf16x8 av[4];
    #pragma unroll
    for (int kb = 0; kb < 4; ++kb) {
        u32x4 o;
        #pragma unroll
        for (int p = 0; p < 4; ++p) {
            unsigned u = avu[kb][p];
            float flo = __builtin_bit_cast(float, u << 16);
            float fhi = __builtin_bit_cast(float, u & 0xFFFF0000u);
            o[p] = pack2(fmaf(flo, rs, nmu), fmaf(fhi, rs, nmu));
        }
        av[kb] = __builtin_bit_cast(bf16x8, o);
    }

    long m = m0 + w * 16 + r;
    u16x4 gvu[8];
    f32x4 bb[8];
    #pragma unroll
    for (int nt = 0; nt < 8; ++nt) {
        gvu[nt] = *(const u16x4*)(gateB + m * 256 + nt * 16 + kq * 4);
        bb[nt]  = *(const f32x4*)(bias2 + 5 * CCH + nt * 16 + kq * 4);
    }

    const char* Wz = (const char*)(wbf + 5 * 16384);
    f32x4 acc[8];
    #pragma unroll
    for (int nt = 0; nt < 8; ++nt) acc[nt] = {0,0,0,0};
    #pragma unroll
    for (int nt = 0; nt < 8; ++nt) {
        int ol = nt * 16 + r;
        int key = ol & 7;
        const char* row = Wz + ol * 256;
        #pragma unroll
        for (int kb = 0; kb < 4; ++kb) {
            bf16x8 bw = *(const bf16x8*)(row + (((kb * 4 + kq) ^ key) << 4));
            acc[nt] = __builtin_amdgcn_mfma_f32_16x16x32_bf16(bw, av[kb], acc[nt], 0, 0, 0);
        }
    }

    __syncthreads();   // ALL gate loads done before any aliasing store

    #pragma unroll
    for (int nt = 0; nt < 8; ++nt) {
        int c0 = nt * 16 + kq * 4;
        f32x4 o;
        #pragma unroll
        for (int j = 0; j < 4; ++j)
            o[j] = (acc[nt][j] + bb[nt][j]) * bf2f(gvu[nt][j]);
        *(f32x4*)(outp + m * CCH + c0) = o;
    }
}

extern "C" void kernel_launch(void* const* d_in, const int* in_sizes, int n_in,
                              void* d_out, int out_size, void* d_ws, size_t ws_size,
                              hipStream_t stream) {
    const float* z       = (const float*)d_in[0];
    const float* mask    = (const float*)d_in[1];
    const float* ln_in_g = (const float*)d_in[2];
    const float* ln_in_b = (const float*)d_in[3];
    const float* w_ag    = (const float*)d_in[4];
    const float* b_ag    = (const float*)d_in[5];
    const float* w_ap    = (const float*)d_in[6];
    const float* b_ap    = (const float*)d_in[7];
    const float* w_bg    = (const float*)d_in[8];
    const float* b_bg    = (const float*)d_in[9];
    const float* w_bp    = (const float*)d_in[10];
    const float* b_bp    = (const float*)d_in[11];
    const float* w_g     = (const float*)d_in[12];
    const float* b_g     = (const float*)d_in[13];
    const float* w_z     = (const float*)d_in[14];
    const float* b_z     = (const float*)d_in[15];
    const float* ln_o_g  = (const float*)d_in[16];
    const float* ln_o_b  = (const float*)d_in[17];
    float* out = (float*)d_out;
    u16* gateB = (u16*)d_out;   // gate bf16 in first 256B of each 512B d_out row

    char* ws = (char*)d_ws;
    const size_t SL = (size_t)MM * CCH * 2;  // 64MB per slot
    u16* xT   = (u16*)ws;
    u16* aT   = (u16*)(ws + SL);
    u16* bT   = (u16*)(ws + 2 * SL);
    u16* wbf  = (u16*)(ws + 3 * SL);                       // 192KB swizzled bf16 weights
    float* b2 = (float*)(ws + 3 * SL + 6 * 16384 * 2);     // 3KB folded biases

    k_prep<<<6, 256, 0, stream>>>(w_ag, w_ap, w_bg, w_bp, w_g, w_z,
                                  b_ag, b_ap, b_bg, b_bp, b_g, b_z,
                                  ln_in_g, ln_in_b, ln_o_g, ln_o_b, wbf, b2);
    k_fused<<<MM / 256, 512, 0, stream>>>(z, mask, wbf, b2, aT, bT, gateB);
    k_tri<<<2048, 256, 0, stream>>>(aT, bT, xT);
    k_out<<<MM / 64, 256, 0, stream>>>(xT, wbf, b2, gateB, out);
}

// Round 17
// 286.373 us; speedup vs baseline: 1.2926x; 1.0543x over previous
//
#include <hip/hip_runtime.h>

#define NN 512
#define CCH 128
#define MM (NN*NN)   // 262144

using f32x4  = __attribute__((ext_vector_type(4))) float;
using f32x2  = __attribute__((ext_vector_type(2))) float;
using f16x8  = __attribute__((ext_vector_type(8))) _Float16;
using u16x4  = __attribute__((ext_vector_type(4))) unsigned short;
using u32x2  = __attribute__((ext_vector_type(2))) unsigned int;
using u32x4  = __attribute__((ext_vector_type(4))) unsigned int;
typedef unsigned short u16;

__device__ __forceinline__ u16 f2h(float f) {
    return __builtin_bit_cast(u16, (_Float16)f);
}
__device__ __forceinline__ float h2f(u16 h) {
    return (float)__builtin_bit_cast(_Float16, h);
}
__device__ __forceinline__ unsigned pack2(float lo, float hi) {
    return (unsigned)f2h(lo) | ((unsigned)f2h(hi) << 16);
}
__device__ __forceinline__ float sigm(float x) { return 1.0f / (1.0f + __expf(-x)); }

__device__ __forceinline__ void gl_lds16(const void* g, void* l) {
    __builtin_amdgcn_global_load_lds(
        (const __attribute__((address_space(1))) void*)g,
        (__attribute__((address_space(3))) void*)l, 16, 0, 0);
}

// ---------------- k_prep: fold LN gamma/beta into fp16 weights + biases ----
// Weight rows stored CHUNK-SWIZZLED: logical 16B chunk q of row o lives at
// physical chunk (q ^ (o&7)).
__global__ __launch_bounds__(256) void k_prep(
    const float* __restrict__ w0, const float* __restrict__ w1,
    const float* __restrict__ w2, const float* __restrict__ w3,
    const float* __restrict__ w4, const float* __restrict__ w5,
    const float* __restrict__ b0, const float* __restrict__ b1,
    const float* __restrict__ b2, const float* __restrict__ b3,
    const float* __restrict__ b4, const float* __restrict__ b5,
    const float* __restrict__ gin, const float* __restrict__ bin,
    const float* __restrict__ gout, const float* __restrict__ bout,
    u16* __restrict__ wbf, float* __restrict__ bias2) {
    int mat = blockIdx.x;
    const float* W = mat==0?w0:mat==1?w1:mat==2?w2:mat==3?w3:mat==4?w4:w5;
    const float* B = mat==0?b0:mat==1?b1:mat==2?b2:mat==3?b3:mat==4?b4:b5;
    const float* G = (mat==5)? gout : gin;
    const float* Bt= (mat==5)? bout : bin;
    __shared__ float gs[CCH], bs[CCH];
    int tid = threadIdx.x;
    if (tid < CCH) { gs[tid] = G[tid]; bs[tid] = Bt[tid]; }
    __syncthreads();
    int o = tid >> 1, c0 = (tid & 1) * 64;
    const float* src = W + o * CCH + c0;
    char* dstrow = (char*)(wbf + mat * 16384) + o * 256;
    int key = o & 7;
    float dot = 0.f;
    #pragma unroll
    for (int q = 0; q < 16; ++q) {
        f32x4 v = *(const f32x4*)(src + q * 4);
        int c = c0 + q * 4;
        dot += bs[c]*v.x + bs[c+1]*v.y + bs[c+2]*v.z + bs[c+3]*v.w;
        u16x4 p;
        p.x = f2h(v.x * gs[c]);     p.y = f2h(v.y * gs[c+1]);
        p.z = f2h(v.z * gs[c+2]);   p.w = f2h(v.w * gs[c+3]);
        int chunk = (c0 >> 3) + (q >> 1);
        *(u16x4*)(dstrow + (((chunk ^ key)) << 4) + ((q & 1) << 3)) = p;
    }
    dot += __shfl_xor(dot, 1);
    if ((tid & 1) == 0) bias2[mat * CCH + o] = B[o] + dot;
}

// ---------------- k_fused: LN(z) + all 5 projections, 128 rows/block -------
// (R13 structure; fp16 intermediates)
__global__ __launch_bounds__(512, 4) void k_fused(
    const float* __restrict__ z, const float* __restrict__ mask,
    const u16* __restrict__ wbf, const float* __restrict__ bias2,
    u16* __restrict__ aT, u16* __restrict__ bT, u16* gateB) {
    __shared__ __align__(16) u16 wls[32768];   // 64KB: two 32KB weight matrices
    int tid = threadIdx.x, w = tid >> 6, lane = tid & 63;
    int r = lane & 15, kq = lane >> 4;
    long m0 = (long)blockIdx.x * 128;

    // stage pair-A weights (mats 0,1 contiguous 64KB) — hides under LN
    {
        const char* Wg = (const char*)wbf;
        #pragma unroll
        for (int it = 0; it < 8; ++it)
            gl_lds16(Wg + (long)it * 8192 + tid * 16, (char*)wls + it * 8192 + w * 1024);
    }

    // LN in registers: lane (w,r,kq) owns row m0+w*16+r, channels kb*32+kq*8+e
    long mrow = m0 + w * 16 + r;
    f16x8 av[4];
    {
        const float* zr = z + mrow * CCH;
        f32x4 zv[4][2];
        float s = 0.f, s2 = 0.f;
        #pragma unroll
        for (int kb = 0; kb < 4; ++kb) {
            zv[kb][0] = *(const f32x4*)(zr + kb * 32 + kq * 8);
            zv[kb][1] = *(const f32x4*)(zr + kb * 32 + kq * 8 + 4);
            #pragma unroll
            for (int h = 0; h < 2; ++h) {
                f32x4 v = zv[kb][h];
                s += v.x + v.y + v.z + v.w;
                s2 = fmaf(v.x, v.x, fmaf(v.y, v.y, fmaf(v.z, v.z, fmaf(v.w, v.w, s2))));
            }
        }
        s  += __shfl_xor(s, 16);  s  += __shfl_xor(s, 32);
        s2 += __shfl_xor(s2, 16); s2 += __shfl_xor(s2, 32);
        float mu = s * (1.0f / CCH);
        float var = fmaxf(s2 * (1.0f / CCH) - mu * mu, 0.f);
        float rs = rsqrtf(var + 1e-5f);
        #pragma unroll
        for (int kb = 0; kb < 4; ++kb) {
            f32x4 a0 = zv[kb][0], a1 = zv[kb][1];
            u32x4 o;
            o[0] = pack2((a0.x - mu) * rs, (a0.y - mu) * rs);
            o[1] = pack2((a0.z - mu) * rs, (a0.w - mu) * rs);
            o[2] = pack2((a1.x - mu) * rs, (a1.y - mu) * rs);
            o[3] = pack2((a1.z - mu) * rs, (a1.w - mu) * rs);
            av[kb] = __builtin_bit_cast(f16x8, o);
        }
    }
    f32x4 mkv = *(const f32x4*)(mask + m0 + w * 16 + kq * 4);

    // bias preload for pair A (overlaps pair-A staging drain)
    float b1v[4][2], b2v[4][2];
    #pragma unroll
    for (int nt = 0; nt < 8; ++nt) {
        b1v[nt >> 1][nt & 1] = bias2[0 * CCH + nt * 16 + r];
        b2v[nt >> 1][nt & 1] = bias2[1 * CCH + nt * 16 + r];
    }

    int i7 = (int)((blockIdx.x >> 2) & 7);
    int q = w * 2 + (kq >> 1);                 // m_local/8 in [0,16)
    long boff = m0 * 2 + ((long)(q >> 3) << 7) + ((long)((q & 7) ^ i7) << 4)
              + ((kq & 1) << 3);

    __syncthreads();   // pair-A staging drained

    // ---- pair A: MFMA ----
    f32x4 acc1[8], acc2[8];
    #pragma unroll
    for (int nt = 0; nt < 8; ++nt) { acc1[nt] = {0,0,0,0}; acc2[nt] = {0,0,0,0}; }
    #pragma unroll
    for (int nt = 0; nt < 8; ++nt) {
        int ol = nt * 16 + r;
        int key = ol & 7;
        const char* row1 = (const char*)wls + ol * 256;
        const char* row2 = (const char*)wls + 32768 + ol * 256;
        #pragma unroll
        for (int kb = 0; kb < 4; ++kb) {
            int ph16 = ((kb * 4 + kq) ^ key) << 4;
            f16x8 b1 = *(const f16x8*)(row1 + ph16);
            f16x8 b2 = *(const f16x8*)(row2 + ph16);
            acc1[nt] = __builtin_amdgcn_mfma_f32_16x16x32_f16(av[kb], b1, acc1[nt], 0, 0, 0);
            acc2[nt] = __builtin_amdgcn_mfma_f32_16x16x32_f16(av[kb], b2, acc2[nt], 0, 0, 0);
        }
    }
    __syncthreads();   // all pair-A wls reads done

    // issue pair-B staging (mats 2,3) — hides under pair-A epilogue
    {
        const char* Wg = (const char*)wbf + 65536;
        #pragma unroll
        for (int it = 0; it < 8; ++it)
            gl_lds16(Wg + (long)it * 8192 + tid * 16, (char*)wls + it * 8192 + w * 1024);
    }

    // ---- pair A epilogue -> aT ----
    #pragma unroll
    for (int nt = 0; nt < 8; ++nt) {
        int cc = nt * 16 + r;
        float bb1 = b1v[nt >> 1][nt & 1], bb2 = b2v[nt >> 1][nt & 1];
        float v0 = mkv[0] * sigm(acc1[nt][0] + bb1) * (acc2[nt][0] + bb2);
        float v1 = mkv[1] * sigm(acc1[nt][1] + bb1) * (acc2[nt][1] + bb2);
        float v2 = mkv[2] * sigm(acc1[nt][2] + bb1) * (acc2[nt][2] + bb2);
        float v3 = mkv[3] * sigm(acc1[nt][3] + bb1) * (acc2[nt][3] + bb2);
        u32x2 pv; pv.x = pack2(v0, v1); pv.y = pack2(v2, v3);
        *(u32x2*)((char*)aT + ((long)cc << 19) + boff) = pv;
    }
    // bias preload for pair B
    #pragma unroll
    for (int nt = 0; nt < 8; ++nt) {
        b1v[nt >> 1][nt & 1] = bias2[2 * CCH + nt * 16 + r];
        b2v[nt >> 1][nt & 1] = bias2[3 * CCH + nt * 16 + r];
    }
    __syncthreads();   // pair-B staged & visible

    // ---- pair B: MFMA ----
    #pragma unroll
    for (int nt = 0; nt < 8; ++nt) { acc1[nt] = {0,0,0,0}; acc2[nt] = {0,0,0,0}; }
    #pragma unroll
    for (int nt = 0; nt < 8; ++nt) {
        int ol = nt * 16 + r;
        int key = ol & 7;
        const char* row1 = (const char*)wls + ol * 256;
        const char* row2 = (const char*)wls + 32768 + ol * 256;
        #pragma unroll
        for (int kb = 0; kb < 4; ++kb) {
            int ph16 = ((kb * 4 + kq) ^ key) << 4;
            f16x8 b1 = *(const f16x8*)(row1 + ph16);
            f16x8 b2 = *(const f16x8*)(row2 + ph16);
            acc1[nt] = __builtin_amdgcn_mfma_f32_16x16x32_f16(av[kb], b1, acc1[nt], 0, 0, 0);
            acc2[nt] = __builtin_amdgcn_mfma_f32_16x16x32_f16(av[kb], b2, acc2[nt], 0, 0, 0);
        }
    }
    __syncthreads();   // all pair-B wls reads done

    // issue gate staging (mat 4, 32KB) — hides under pair-B epilogue
    {
        const char* Wg = (const char*)wbf + 131072;
        #pragma unroll
        for (int it = 0; it < 4; ++it)
            gl_lds16(Wg + (long)it * 8192 + tid * 16, (char*)wls + it * 8192 + w * 1024);
    }

    // ---- pair B epilogue -> bT ----
    #pragma unroll
    for (int nt = 0; nt < 8; ++nt) {
        int cc = nt * 16 + r;
        float bb1 = b1v[nt >> 1][nt & 1], bb2 = b2v[nt >> 1][nt & 1];
        float v0 = mkv[0] * sigm(acc1[nt][0] + bb1) * (acc2[nt][0] + bb2);
        float v1 = mkv[1] * sigm(acc1[nt][1] + bb1) * (acc2[nt][1] + bb2);
        float v2 = mkv[2] * sigm(acc1[nt][2] + bb1) * (acc2[nt][2] + bb2);
        float v3 = mkv[3] * sigm(acc1[nt][3] + bb1) * (acc2[nt][3] + bb2);
        u32x2 pv; pv.x = pack2(v0, v1); pv.y = pack2(v2, v3);
        *(u32x2*)((char*)bT + ((long)cc << 19) + boff) = pv;
    }
    // gate bias preload
    f32x4 bg[8];
    #pragma unroll
    for (int nt = 0; nt < 8; ++nt)
        bg[nt] = *(const f32x4*)(bias2 + 4 * CCH + nt * 16 + kq * 4);
    __syncthreads();   // gate staged & visible

    // ---- gate: mfma(W, zn) swapped -> j-regs = 4 consecutive c ----
    {
        f32x4 acc[8];
        #pragma unroll
        for (int nt = 0; nt < 8; ++nt) acc[nt] = {0,0,0,0};
        #pragma unroll
        for (int nt = 0; nt < 8; ++nt) {
            int ol = nt * 16 + r;
            int key = ol & 7;
            const char* row1 = (const char*)wls + ol * 256;
            #pragma unroll
            for (int kb = 0; kb < 4; ++kb) {
                f16x8 b1 = *(const f16x8*)(row1 + (((kb * 4 + kq) ^ key) << 4));
                acc[nt] = __builtin_amdgcn_mfma_f32_16x16x32_f16(b1, av[kb], acc[nt], 0, 0, 0);
            }
        }
        #pragma unroll
        for (int nt = 0; nt < 8; ++nt) {
            int c0 = nt * 16 + kq * 4;
            u32x2 pv;
            pv.x = pack2(sigm(acc[nt][0] + bg[nt][0]), sigm(acc[nt][1] + bg[nt][1]));
            pv.y = pack2(sigm(acc[nt][2] + bg[nt][2]), sigm(acc[nt][3] + bg[nt][3]));
            *(u32x2*)(gateB + mrow * 256 + c0) = pv;
        }
    }
}

// ---------------- k_tri: per-channel triangle GEMM, BK=64 ------------------
__global__ __launch_bounds__(256, 4) void k_tri(const u16* __restrict__ aT,
                                                const u16* __restrict__ bT,
                                                u16* __restrict__ xT) {
    __shared__ __align__(16) char shm[34816];
    u16* At = (u16*)shm;
    u16* Bt = (u16*)(shm + 16384);
    int tid = threadIdx.x;
    int w = tid >> 6, lane = tid & 63;
    int r = lane & 15, kq = lane >> 4;

    int L = blockIdx.x;
    int xcd = L & 7, idx = L >> 3;
    int c    = xcd + 8 * (idx >> 4);
    int tile = idx & 15;
    int ti = tile >> 2, tj = tile & 3;

    const char* abase = (const char*)(aT + (long)c * MM) + (long)(ti * 128) * 1024;
    const char* bbase = (const char*)(bT + (long)c * MM) + (long)(tj * 128) * 1024;
    int wm = w >> 1, wn = w & 1;

    f32x4 acc[4][4];
    #pragma unroll
    for (int a = 0; a < 4; ++a)
        #pragma unroll
        for (int bq = 0; bq < 4; ++bq) acc[a][bq] = {0.f,0.f,0.f,0.f};

    for (int ks = 0; ks < 8; ++ks) {
        const char* asrc = abase + ks * 128;
        const char* bsrc = bbase + ks * 128;
        #pragma unroll
        for (int it = 0; it < 4; ++it) {
            int u = it * 256 + tid;
            long goff = (long)(u >> 3) * 1024 + (u & 7) * 16;
            gl_lds16(asrc + goff, (char*)At + it * 4096 + w * 1024);
            gl_lds16(bsrc + goff, (char*)Bt + it * 4096 + w * 1024);
        }
        __syncthreads();

        #pragma unroll
        for (int kh = 0; kh < 2; ++kh) {
            f16x8 af[4];
            #pragma unroll
            for (int mt = 0; mt < 4; ++mt) {
                int rowa = wm * 64 + mt * 16 + r;
                af[mt] = *(const f16x8*)((const char*)At + rowa * 128 +
                                         (((kh * 4 + kq) ^ (r & 7)) << 4));
            }
            #pragma unroll
            for (int nt = 0; nt < 4; ++nt) {
                int rowb = wn * 64 + nt * 16 + r;
                f16x8 bf = *(const f16x8*)((const char*)Bt + rowb * 128 +
                                           (((kh * 4 + kq) ^ (r & 7)) << 4));
                #pragma unroll
                for (int mt = 0; mt < 4; ++mt)
                    acc[mt][nt] = __builtin_amdgcn_mfma_f32_16x16x32_f16(bf, af[mt], acc[mt][nt], 0, 0, 0);
            }
        }
        __syncthreads();
    }

    char* tb = shm;
    #pragma unroll
    for (int mt = 0; mt < 4; ++mt) {
        int il = wm * 64 + mt * 16 + r;
        #pragma unroll
        for (int nt = 0; nt < 4; ++nt) {
            int jl = wn * 64 + nt * 16 + kq * 4;
            u32x2 pv;
            pv.x = pack2(acc[mt][nt][0], acc[mt][nt][1]);
            pv.y = pack2(acc[mt][nt][2], acc[mt][nt][3]);
            *(u32x2*)(tb + il * 272 + jl * 2) = pv;
        }
    }
    __syncthreads();
    u16* xrow = xT + (long)c * MM + (long)(ti * 128) * NN + tj * 128;
    int joff = tid & 15;
    #pragma unroll
    for (int rd = 0; rd < 8; ++rd) {
        int il = rd * 16 + (tid >> 4);
        u32x4 vv = *(const u32x4*)(tb + il * 272 + joff * 16);
        *(u32x4*)(xrow + (long)il * NN + joff * 8) = vv;
    }
}

// ---------------- k_out: LN(x) @ w_z''^T + bias2_z, * gate -----------------
// Epilogue routed through padded LDS f32 tile -> fully coalesced stores.
__global__ __launch_bounds__(256, 4) void k_out(const u16* __restrict__ xT,
                                                const u16* __restrict__ wbf,
                                                const float* __restrict__ bias2,
                                                const u16* gateB,
                                                float* __restrict__ outp) {
    __shared__ __align__(16) char shm[34816];  // u16 transpose (16KB) then f32 tile [64][132]
    u16* xl = (u16*)shm;
    int tid = threadIdx.x, w = tid >> 6, lane = tid & 63;
    int r = lane & 15, kq = lane >> 4;
    long m0 = (long)blockIdx.x * 64;

    // transpose stage: xT[c][m] -> xl[m][c], 4 channels packed per u16x4
    {
        int cg = tid & 31, ms = tid >> 5;
        int c0 = cg * 4;
        const u16* base = xT + m0 + (long)ms * 8;
        u16x4 t;
        const u16* s0 = base + (long)(c0 + 0) * MM;
        const u16* s1 = base + (long)(c0 + 1) * MM;
        const u16* s2 = base + (long)(c0 + 2) * MM;
        const u16* s3 = base + (long)(c0 + 3) * MM;
        #pragma unroll
        for (int e = 0; e < 8; ++e) {
            int m = ms * 8 + e;
            t.x = s0[e]; t.y = s1[e]; t.z = s2[e]; t.w = s3[e];
            *(u16x4*)((char*)xl + m * 256 + ((c0 * 2) ^ ((m & 15) << 4))) = t;
        }
    }
    __syncthreads();

    // A-frags as u32 pairs + LN stats (fp16 decode)
    int mlr = w * 16 + r;
    int swm = (mlr & 15) << 4;
    u32x4 avu[4];
    float s = 0.f, s2 = 0.f;
    #pragma unroll
    for (int kb = 0; kb < 4; ++kb) {
        avu[kb] = *(const u32x4*)((const char*)xl + mlr * 256 + ((kb * 64 + kq * 16) ^ swm));
        #pragma unroll
        for (int p = 0; p < 4; ++p) {
            unsigned u = avu[kb][p];
            float flo = h2f((u16)(u & 0xFFFFu));
            float fhi = h2f((u16)(u >> 16));
            s += flo + fhi;
            s2 = fmaf(flo, flo, s2);
            s2 = fmaf(fhi, fhi, s2);
        }
    }
    s  += __shfl_xor(s, 16);  s  += __shfl_xor(s, 32);
    s2 += __shfl_xor(s2, 16); s2 += __shfl_xor(s2, 32);
    float mu = s * (1.0f / CCH);
    float var = fmaxf(s2 * (1.0f / CCH) - mu * mu, 0.f);
    float rs = rsqrtf(var + 1e-5f);
    float nmu = -mu * rs;
    f16x8 av[4];
    #pragma unroll
    for (int kb = 0; kb < 4; ++kb) {
        u32x4 o;
        #pragma unroll
        for (int p = 0; p < 4; ++p) {
            unsigned u = avu[kb][p];
            float flo = h2f((u16)(u & 0xFFFFu));
            float fhi = h2f((u16)(u >> 16));
            o[p] = pack2(fmaf(flo, rs, nmu), fmaf(fhi, rs, nmu));
        }
        av[kb] = __builtin_bit_cast(f16x8, o);
    }

    // gate + bias preload (gateB aliases outp rows of THIS block only)
    long m = m0 + w * 16 + r;
    u16x4 gvu[8];
    f32x4 bb[8];
    #pragma unroll
    for (int nt = 0; nt < 8; ++nt) {
        gvu[nt] = *(const u16x4*)(gateB + m * 256 + nt * 16 + kq * 4);
        bb[nt]  = *(const f32x4*)(bias2 + 5 * CCH + nt * 16 + kq * 4);
    }

    // swapped MFMA vs w_z'' (global reads, chunk-swizzled layout)
    const char* Wz = (const char*)(wbf + 5 * 16384);
    f32x4 acc[8];
    #pragma unroll
    for (int nt = 0; nt < 8; ++nt) acc[nt] = {0,0,0,0};
    #pragma unroll
    for (int nt = 0; nt < 8; ++nt) {
        int ol = nt * 16 + r;
        int key = ol & 7;
        const char* row = Wz + ol * 256;
        #pragma unroll
        for (int kb = 0; kb < 4; ++kb) {
            f16x8 bw = *(const f16x8*)(row + (((kb * 4 + kq) ^ key) << 4));
            acc[nt] = __builtin_amdgcn_mfma_f32_16x16x32_f16(bw, av[kb], acc[nt], 0, 0, 0);
        }
    }

    __syncthreads();   // all xl reads + all gate preloads done block-wide

    // epilogue -> padded LDS f32 tile [64 m][132 f32] (pitch 528B)
    {
        char* tile = shm;
        int ml = w * 16 + r;
        #pragma unroll
        for (int nt = 0; nt < 8; ++nt) {
            int c0 = nt * 16 + kq * 4;
            f32x4 o;
            #pragma unroll
            for (int j = 0; j < 4; ++j)
                o[j] = (acc[nt][j] + bb[nt][j]) * h2f(gvu[nt][j]);
            *(f32x4*)(tile + ml * 528 + c0 * 4) = o;
        }
    }
    __syncthreads();

    // fully coalesced stores: 8 rounds, each wave inst = 2 complete rows (1KB)
    {
        const char* tile = shm;
        int part = tid & 31;
        #pragma unroll
        for (int rd = 0; rd < 8; ++rd) {
            int ml = rd * 8 + (tid >> 5);
            f32x4 v = *(const f32x4*)(tile + ml * 528 + part * 16);
            *(f32x4*)(outp + (m0 + ml) * CCH + part * 4) = v;
        }
    }
}

extern "C" void kernel_launch(void* const* d_in, const int* in_sizes, int n_in,
                              void* d_out, int out_size, void* d_ws, size_t ws_size,
                              hipStream_t stream) {
    const float* z       = (const float*)d_in[0];
    const float* mask    = (const float*)d_in[1];
    const float* ln_in_g = (const float*)d_in[2];
    const float* ln_in_b = (const float*)d_in[3];
    const float* w_ag    = (const float*)d_in[4];
    const float* b_ag    = (const float*)d_in[5];
    const float* w_ap    = (const float*)d_in[6];
    const float* b_ap    = (const float*)d_in[7];
    const float* w_bg    = (const float*)d_in[8];
    const float* b_bg    = (const float*)d_in[9];
    const float* w_bp    = (const float*)d_in[10];
    const float* b_bp    = (const float*)d_in[11];
    const float* w_g     = (const float*)d_in[12];
    const float* b_g     = (const float*)d_in[13];
    const float* w_z     = (const float*)d_in[14];
    const float* b_z     = (const float*)d_in[15];
    const float* ln_o_g  = (const float*)d_in[16];
    const float* ln_o_b  = (const float*)d_in[17];
    float* out = (float*)d_out;
    u16* gateB = (u16*)d_out;   // gate fp16 in first 256B of each 512B d_out row

    char* ws = (char*)d_ws;
    const size_t SL = (size_t)MM * CCH * 2;  // 64MB per slot
    u16* xT   = (u16*)ws;
    u16* aT   = (u16*)(ws + SL);
    u16* bT   = (u16*)(ws + 2 * SL);
    u16* wbf  = (u16*)(ws + 3 * SL);                       // 192KB swizzled fp16 weights
    float* b2 = (float*)(ws + 3 * SL + 6 * 16384 * 2);     // 3KB folded biases

    k_prep<<<6, 256, 0, stream>>>(w_ag, w_ap, w_bg, w_bp, w_g, w_z,
                                  b_ag, b_ap, b_bg, b_bp, b_g, b_z,
                                  ln_in_g, ln_in_b, ln_o_g, ln_o_b, wbf, b2);
    k_fused<<<MM / 128, 512, 0, stream>>>(z, mask, wbf, b2, aT, bT, gateB);
    k_tri<<<2048, 256, 0, stream>>>(aT, bT, xT);
    k_out<<<MM / 64, 256, 0, stream>>>(xT, wbf, b2, gateB, out);
}